// Round 12
// baseline (111.966 us; speedup 1.0000x reference)
//
#include <hip/hip_runtime.h>
#include <stdint.h>

// Problem constants (fixed by the reference)
#define NB    32768   // batch
#define NS    16      // states per element
#define SS    32      // state size (K of stage 1)
#define ENCD  64      // encoder width
#define HIDD  128     // hidden width
#define OUTD  8       // output logits
#define BT    16      // batch elements per block
#define THREADS 256   // 4 waves

typedef _Float16 half8  __attribute__((ext_vector_type(8)));  // 8 f16 = 4 VGPRs
typedef __fp16   fp16x2 __attribute__((ext_vector_type(2)));  // cvt_pkrtz result type
typedef float    f32x4  __attribute__((ext_vector_type(4)));

#define MFMA(a, b, c) __builtin_amdgcn_mfma_f32_16x16x32_f16((a), (b), (c), 0, 0, 0)

// Split 8 floats into fp16 hi + lo: f = hi + lo + O(2^-20 |f|).
// Used for ACTIVATIONS (A-side) and the final layer only.
__device__ __forceinline__ void split8(const float* f, half8& hi, half8& lo) {
#pragma unroll
  for (int j = 0; j < 8; j += 2) {
    fp16x2 h  = __builtin_amdgcn_cvt_pkrtz(f[j], f[j + 1]);
    float  r0 = f[j]     - (float)h[0];
    float  r1 = f[j + 1] - (float)h[1];
    fp16x2 l2 = __builtin_amdgcn_cvt_pkrtz(r0, r1);
    hi[j] = (_Float16)(float)h[0];  hi[j + 1] = (_Float16)(float)h[1];
    lo[j] = (_Float16)(float)l2[0]; lo[j + 1] = (_Float16)(float)l2[1];
  }
}

// hi-only weight conversion (RTN casts, rel err 2^-12) — r10, kept.
__device__ __forceinline__ void cvt8(const float* f, half8& hi) {
#pragma unroll
  for (int j = 0; j < 8; ++j)
    hi[j] = (_Float16)f[j];
}

// R11 post-mortem: interleaving the two stage-3 accumulator chains gained
// -1.3us with prediction MATCHED -> dependent-MFMA latency is the residual.
// R12 finishes the pattern: (a) stage 3 splits each acc into hi/lo partials
// -> 4 independent 4-deep chains (was 2x 8-deep); (b) stage 4 splits its
// single 12-deep chain into 3 product streams (hi*bhi, lo*bhi, hi*blo) ->
// 3x 4-deep. Partial sums combined with f32x4 adds (fp32 reassociation only,
// ~1e-7 vs 9.8e-4 absmax). Regs +16, inside the (256,4)=128 cap.
__global__ __launch_bounds__(THREADS, 4)
void gnn_fused(const float* __restrict__ obs,
               const float* __restrict__ W_enc,
               const float* __restrict__ b_enc,
               const float* __restrict__ W_f,
               const float* __restrict__ b_f,
               const float* __restrict__ W_dec,
               const float* __restrict__ b_dec,
               float* __restrict__ out)
{
  // stride 132 floats: rows 528 B (16B-aligned), row-to-row bank shift of 4
  __shared__ __align__(16) float f_in[BT][132];   // stage-2 output [batch][128]
  __shared__ __align__(16) float hidn[BT][132];   // stage-3 output [batch][128]

  const int tid  = threadIdx.x;
  const int w    = tid >> 6;     // wave 0..3
  const int l    = tid & 63;     // lane
  const int m15  = l & 15;
  const int quad = l >> 4;
  const int b0   = blockIdx.x * BT;

  // ---- stage-1 B-fragments: W_enc[k][e] columns, hi-only fp16 (16 VGPRs)
  half8 we_hi[4];
  float benc[4];
#pragma unroll
  for (int nt = 0; nt < 4; ++nt) {
    float f[8];
#pragma unroll
    for (int j = 0; j < 8; ++j)
      f[j] = W_enc[(size_t)(quad * 8 + j) * ENCD + nt * 16 + m15];
    cvt8(f, we_hi[nt]);
    benc[nt] = b_enc[nt * 16 + m15];
  }

  // ================= stage 1 (enc MFMA) + stage 2 (masked mean-pool) =========
  // wave handles batches [b0 + w*4, b0 + w*4 + 4), depth-1 rotating prefetch
  const float* bp = obs + (size_t)(b0 + w * 4) * (NS * SS) + m15 * SS + quad * 8;
  float4 c0 = ((const float4*)bp)[0];
  float4 c1 = ((const float4*)bp)[1];
#pragma unroll
  for (int i = 0; i < 4; ++i) {
    float4 n0, n1;
    if (i < 3) {  // prefetch next batch element
      const float* np = bp + (size_t)(i + 1) * (NS * SS);
      n0 = ((const float4*)np)[0];
      n1 = ((const float4*)np)[1];
    } else { n0 = c0; n1 = c1; }

    float f[8] = {c0.x, c0.y, c0.z, c0.w, c1.x, c1.y, c1.z, c1.w};

    // flags: lanes 0..15 hold states[b][n][0]; cumprod run length via ballot+ctz
    unsigned long long bal = __ballot((l < 16) && (f[0] == 1.0f));
    int run = __builtin_ctzll(~(bal >> 1));      // consecutive valid neighbors
    float inv = 1.0f / fmaxf((float)run, 1.0f);

    half8 ahi, alo;
    split8(f, ahi, alo);                         // A keeps hi+lo (exact-ish)

    const int bi = w * 4 + i;  // local batch row
#pragma unroll
    for (int nt = 0; nt < 4; ++nt) {
      f32x4 acc = {0.f, 0.f, 0.f, 0.f};
      acc = MFMA(ahi, we_hi[nt], acc);           // 2-deep, 4 independent nt
      acc = MFMA(alo, we_hi[nt], acc);           // chains: already ILP-rich
      // D layout: lane holds enc[n = quad*4 + r][e = nt*16 + m15]
      float s = 0.f, e0 = 0.f;
#pragma unroll
      for (int r = 0; r < 4; ++r) {
        int n = quad * 4 + r;
        float v = fmaxf(acc[r] + benc[nt], 0.f);
        if (n == 0) e0 = v;                    // agent row
        if (n >= 1 && n <= run) s += v;        // valid neighbor
      }
      s += __shfl_xor(s, 16, 64);              // reduce across quads
      s += __shfl_xor(s, 32, 64);
      if (quad == 0) {
        f_in[bi][nt * 16 + m15]      = e0;      // agent_enc
        f_in[bi][64 + nt * 16 + m15] = s * inv; // agg
      }
    }
    c0 = n0; c1 = n1;
  }
  __syncthreads();

  // ================= stage 3: hidden = relu(f_in @ W_f + b_f) ================
  // single 16-row M-tile; wave w covers N-tiles 2w, 2w+1. Both streams AND
  // hi/lo partials split: 4 independent 4-deep MFMA chains per wave.
  {
    half8 fa_hi[4], fa_lo[4];
#pragma unroll
    for (int ks = 0; ks < 4; ++ks) {
      const float4* p = (const float4*)&f_in[m15][ks * 32 + quad * 8];
      float4 a = p[0], b = p[1];
      float f[8] = {a.x, a.y, a.z, a.w, b.x, b.y, b.z, b.w};
      split8(f, fa_hi[ks], fa_lo[ks]);           // activations keep hi+lo
    }
    const int   h0  = (w * 2) * 16 + m15;        // tt=0 column
    const int   h1  = (w * 2 + 1) * 16 + m15;    // tt=1 column
    const float bf0 = b_f[h0];
    const float bf1 = b_f[h1];

    float cur0[8], cur1[8], nxt0[8], nxt1[8];
#pragma unroll
    for (int j = 0; j < 8; ++j) {                // ks=0 fragments, both streams
      cur0[j] = W_f[(size_t)(quad * 8 + j) * HIDD + h0];
      cur1[j] = W_f[(size_t)(quad * 8 + j) * HIDD + h1];
    }

    f32x4 acc0h = {0.f, 0.f, 0.f, 0.f};
    f32x4 acc0l = {0.f, 0.f, 0.f, 0.f};
    f32x4 acc1h = {0.f, 0.f, 0.f, 0.f};
    f32x4 acc1l = {0.f, 0.f, 0.f, 0.f};
#pragma unroll
    for (int ks = 0; ks < 4; ++ks) {
      if (ks < 3) {                              // prefetch ks+1, both streams
#pragma unroll
        for (int j = 0; j < 8; ++j) {
          const size_t row = (size_t)((ks + 1) * 32 + quad * 8 + j) * HIDD;
          nxt0[j] = W_f[row + h0];
          nxt1[j] = W_f[row + h1];
        }
      }
      half8 b0h, b1h;
      cvt8(cur0, b0h);
      cvt8(cur1, b1h);
      acc0h = MFMA(fa_hi[ks], b0h, acc0h);       // 4 INDEPENDENT MFMAs:
      acc1h = MFMA(fa_hi[ks], b1h, acc1h);       // no chain dependency
      acc0l = MFMA(fa_lo[ks], b0h, acc0l);       // within a ks step
      acc1l = MFMA(fa_lo[ks], b1h, acc1l);
#pragma unroll
      for (int j = 0; j < 8; ++j) { cur0[j] = nxt0[j]; cur1[j] = nxt1[j]; }
    }
    const f32x4 acc0 = acc0h + acc0l;            // combine partials (fp32)
    const f32x4 acc1 = acc1h + acc1l;
#pragma unroll
    for (int r = 0; r < 4; ++r) {                // D: row = batch, col = h
      hidn[quad * 4 + r][h0] = fmaxf(acc0[r] + bf0, 0.f);
      hidn[quad * 4 + r][h1] = fmaxf(acc1[r] + bf1, 0.f);
    }
  }
  __syncthreads();

  // ================= stage 4: logits = hidden @ W_dec + b_dec ================
  // wave 0 only — FULL hi+lo precision kept. 12-deep chain split into the 3
  // product streams -> 3 independent 4-deep chains.
  if (w == 0) {
    half8 ga_hi[4], ga_lo[4];
#pragma unroll
    for (int ks = 0; ks < 4; ++ks) {
      const float4* p = (const float4*)&hidn[m15][ks * 32 + quad * 8];
      float4 a = p[0], b = p[1];
      float f[8] = {a.x, a.y, a.z, a.w, b.x, b.y, b.z, b.w};
      split8(f, ga_hi[ks], ga_lo[ks]);
    }
    f32x4 aA = {0.f, 0.f, 0.f, 0.f};             // hi * bhi
    f32x4 aB = {0.f, 0.f, 0.f, 0.f};             // lo * bhi
    f32x4 aC = {0.f, 0.f, 0.f, 0.f};             // hi * blo
#pragma unroll
    for (int ks = 0; ks < 4; ++ks) {
      float f[8];
#pragma unroll
      for (int j = 0; j < 8; ++j) {
        int k = ks * 32 + quad * 8 + j;
        f[j] = (m15 < OUTD) ? W_dec[(size_t)k * OUTD + m15] : 0.f;  // pad N 8->16
      }
      half8 bhi, blo;
      split8(f, bhi, blo);
      aA = MFMA(ga_hi[ks], bhi, aA);             // 3 independent chains
      aB = MFMA(ga_lo[ks], bhi, aB);
      aC = MFMA(ga_hi[ks], blo, aC);
    }
    const f32x4 acc = (aA + aB) + aC;            // combine partials (fp32)
    if (m15 < OUTD) {
      const float bd = b_dec[m15];
#pragma unroll
      for (int r = 0; r < 4; ++r) {
        const int m = quad * 4 + r;
        out[(size_t)(b0 + m) * OUTD + m15] = acc[r] + bd;
      }
    }
  }
}

extern "C" void kernel_launch(void* const* d_in, const int* in_sizes, int n_in,
                              void* d_out, int out_size, void* d_ws, size_t ws_size,
                              hipStream_t stream) {
  (void)in_sizes; (void)n_in; (void)d_ws; (void)ws_size; (void)out_size;
  const float* obs   = (const float*)d_in[0];
  const float* W_enc = (const float*)d_in[1];
  const float* b_enc = (const float*)d_in[2];
  const float* W_f   = (const float*)d_in[3];
  const float* b_f   = (const float*)d_in[4];
  const float* W_dec = (const float*)d_in[5];
  const float* b_dec = (const float*)d_in[6];
  float* out = (float*)d_out;

  dim3 grid(NB / BT);      // 2048 blocks
  dim3 block(THREADS);     // 256 threads = 4 waves
  gnn_fused<<<grid, block, 0, stream>>>(obs, W_enc, b_enc, W_f, b_f, W_dec, b_dec, out);
}

// Round 13
// 111.041 us; speedup vs baseline: 1.0083x; 1.0083x over previous
//
#include <hip/hip_runtime.h>
#include <stdint.h>

// Problem constants (fixed by the reference)
#define NB    32768   // batch
#define NS    16      // states per element
#define SS    32      // state size (K of stage 1)
#define ENCD  64      // encoder width
#define HIDD  128     // hidden width
#define OUTD  8       // output logits
#define BT    16      // batch elements per block
#define THREADS 256   // 4 waves

typedef _Float16 half8  __attribute__((ext_vector_type(8)));  // 8 f16 = 4 VGPRs
typedef __fp16   fp16x2 __attribute__((ext_vector_type(2)));  // cvt_pkrtz result type
typedef float    f32x4  __attribute__((ext_vector_type(4)));

#define MFMA(a, b, c) __builtin_amdgcn_mfma_f32_16x16x32_f16((a), (b), (c), 0, 0, 0)

// Split 8 floats into fp16 hi + lo: f = hi + lo + O(2^-20 |f|).
// Used for ACTIVATIONS (A-side) and the final layer only.
__device__ __forceinline__ void split8(const float* f, half8& hi, half8& lo) {
#pragma unroll
  for (int j = 0; j < 8; j += 2) {
    fp16x2 h  = __builtin_amdgcn_cvt_pkrtz(f[j], f[j + 1]);
    float  r0 = f[j]     - (float)h[0];
    float  r1 = f[j + 1] - (float)h[1];
    fp16x2 l2 = __builtin_amdgcn_cvt_pkrtz(r0, r1);
    hi[j] = (_Float16)(float)h[0];  hi[j + 1] = (_Float16)(float)h[1];
    lo[j] = (_Float16)(float)l2[0]; lo[j + 1] = (_Float16)(float)l2[1];
  }
}

// hi-only weight conversion (RTN casts, rel err 2^-12) — r10, kept.
__device__ __forceinline__ void cvt8(const float* f, half8& hi) {
#pragma unroll
  for (int j = 0; j < 8; ++j)
    hi[j] = (_Float16)f[j];
}

// FINAL (r13 = r11 verbatim, session best 109.9us). Session findings:
//  - r11 (-1.3us, prediction matched): stage-3's two 8-deep dependent MFMA
//    chains interleaved -> 2-way ILP. This is the optimum; 4-way (r12)
//    regresses via register pressure (+2.1us).
//  - r10 (-0.5us): weights hi-only fp16 (RTN); activations keep hi+lo.
//    absmax 9.77e-4 = f16 weight quantum; no further precision headroom.
//  - All schedule-pinning (sched_barrier/FIFO load groups) regresses (r3,r9).
//  - (256,4): VGPR cap 128, no spill; (256,6/8) spill via WRITE_SIZE blowup (r2,r4).
//  - Structure is latency-floored: kernel ~26us vs ~11us HBM floor; both
//    ILP (r12) and TLP (r4/r6) directions measurably passed their optima.
__global__ __launch_bounds__(THREADS, 4)
void gnn_fused(const float* __restrict__ obs,
               const float* __restrict__ W_enc,
               const float* __restrict__ b_enc,
               const float* __restrict__ W_f,
               const float* __restrict__ b_f,
               const float* __restrict__ W_dec,
               const float* __restrict__ b_dec,
               float* __restrict__ out)
{
  // stride 132 floats: rows 528 B (16B-aligned), row-to-row bank shift of 4
  __shared__ __align__(16) float f_in[BT][132];   // stage-2 output [batch][128]
  __shared__ __align__(16) float hidn[BT][132];   // stage-3 output [batch][128]

  const int tid  = threadIdx.x;
  const int w    = tid >> 6;     // wave 0..3
  const int l    = tid & 63;     // lane
  const int m15  = l & 15;
  const int quad = l >> 4;
  const int b0   = blockIdx.x * BT;

  // ---- stage-1 B-fragments: W_enc[k][e] columns, hi-only fp16 (16 VGPRs)
  half8 we_hi[4];
  float benc[4];
#pragma unroll
  for (int nt = 0; nt < 4; ++nt) {
    float f[8];
#pragma unroll
    for (int j = 0; j < 8; ++j)
      f[j] = W_enc[(size_t)(quad * 8 + j) * ENCD + nt * 16 + m15];
    cvt8(f, we_hi[nt]);
    benc[nt] = b_enc[nt * 16 + m15];
  }

  // ================= stage 1 (enc MFMA) + stage 2 (masked mean-pool) =========
  // wave handles batches [b0 + w*4, b0 + w*4 + 4), depth-1 rotating prefetch
  const float* bp = obs + (size_t)(b0 + w * 4) * (NS * SS) + m15 * SS + quad * 8;
  float4 c0 = ((const float4*)bp)[0];
  float4 c1 = ((const float4*)bp)[1];
#pragma unroll
  for (int i = 0; i < 4; ++i) {
    float4 n0, n1;
    if (i < 3) {  // prefetch next batch element
      const float* np = bp + (size_t)(i + 1) * (NS * SS);
      n0 = ((const float4*)np)[0];
      n1 = ((const float4*)np)[1];
    } else { n0 = c0; n1 = c1; }

    float f[8] = {c0.x, c0.y, c0.z, c0.w, c1.x, c1.y, c1.z, c1.w};

    // flags: lanes 0..15 hold states[b][n][0]; cumprod run length via ballot+ctz
    unsigned long long bal = __ballot((l < 16) && (f[0] == 1.0f));
    int run = __builtin_ctzll(~(bal >> 1));      // consecutive valid neighbors
    float inv = 1.0f / fmaxf((float)run, 1.0f);

    half8 ahi, alo;
    split8(f, ahi, alo);                         // A keeps hi+lo (exact-ish)

    const int bi = w * 4 + i;  // local batch row
#pragma unroll
    for (int nt = 0; nt < 4; ++nt) {
      f32x4 acc = {0.f, 0.f, 0.f, 0.f};
      acc = MFMA(ahi, we_hi[nt], acc);           // 2 MFMAs (B-lo dropped, r10)
      acc = MFMA(alo, we_hi[nt], acc);
      // D layout: lane holds enc[n = quad*4 + r][e = nt*16 + m15]
      float s = 0.f, e0 = 0.f;
#pragma unroll
      for (int r = 0; r < 4; ++r) {
        int n = quad * 4 + r;
        float v = fmaxf(acc[r] + benc[nt], 0.f);
        if (n == 0) e0 = v;                    // agent row
        if (n >= 1 && n <= run) s += v;        // valid neighbor
      }
      s += __shfl_xor(s, 16, 64);              // reduce across quads
      s += __shfl_xor(s, 32, 64);
      if (quad == 0) {
        f_in[bi][nt * 16 + m15]      = e0;      // agent_enc
        f_in[bi][64 + nt * 16 + m15] = s * inv; // agg
      }
    }
    c0 = n0; c1 = n1;
  }
  __syncthreads();

  // ================= stage 3: hidden = relu(f_in @ W_f + b_f) ================
  // single 16-row M-tile; wave w covers N-tiles 2w, 2w+1 — BOTH streams run
  // simultaneously: interleaved acc0/acc1 chains, 16 W_f loads in flight.
  {
    half8 fa_hi[4], fa_lo[4];
#pragma unroll
    for (int ks = 0; ks < 4; ++ks) {
      const float4* p = (const float4*)&f_in[m15][ks * 32 + quad * 8];
      float4 a = p[0], b = p[1];
      float f[8] = {a.x, a.y, a.z, a.w, b.x, b.y, b.z, b.w};
      split8(f, fa_hi[ks], fa_lo[ks]);           // activations keep hi+lo
    }
    const int   h0  = (w * 2) * 16 + m15;        // tt=0 column
    const int   h1  = (w * 2 + 1) * 16 + m15;    // tt=1 column
    const float bf0 = b_f[h0];
    const float bf1 = b_f[h1];

    float cur0[8], cur1[8], nxt0[8], nxt1[8];
#pragma unroll
    for (int j = 0; j < 8; ++j) {                // ks=0 fragments, both streams
      cur0[j] = W_f[(size_t)(quad * 8 + j) * HIDD + h0];
      cur1[j] = W_f[(size_t)(quad * 8 + j) * HIDD + h1];
    }

    f32x4 acc0 = {0.f, 0.f, 0.f, 0.f};
    f32x4 acc1 = {0.f, 0.f, 0.f, 0.f};
#pragma unroll
    for (int ks = 0; ks < 4; ++ks) {
      if (ks < 3) {                              // prefetch ks+1, both streams
#pragma unroll
        for (int j = 0; j < 8; ++j) {
          const size_t row = (size_t)((ks + 1) * 32 + quad * 8 + j) * HIDD;
          nxt0[j] = W_f[row + h0];
          nxt1[j] = W_f[row + h1];
        }
      }
      half8 b0h, b1h;
      cvt8(cur0, b0h);
      cvt8(cur1, b1h);
      acc0 = MFMA(fa_hi[ks], b0h, acc0);         // chains interleaved:
      acc1 = MFMA(fa_hi[ks], b1h, acc1);         // acc0/acc1 alternate, each
      acc0 = MFMA(fa_lo[ks], b0h, acc0);         // chain's internal order is
      acc1 = MFMA(fa_lo[ks], b1h, acc1);         // unchanged (same numerics)
#pragma unroll
      for (int j = 0; j < 8; ++j) { cur0[j] = nxt0[j]; cur1[j] = nxt1[j]; }
    }
#pragma unroll
    for (int r = 0; r < 4; ++r) {                // D: row = batch, col = h
      hidn[quad * 4 + r][h0] = fmaxf(acc0[r] + bf0, 0.f);
      hidn[quad * 4 + r][h1] = fmaxf(acc1[r] + bf1, 0.f);
    }
  }
  __syncthreads();

  // ================= stage 4: logits = hidden @ W_dec + b_dec ================
  // wave 0 only — FULL hi+lo precision kept (last layer feeds absmax directly)
  if (w == 0) {
    half8 ga_hi[4], ga_lo[4];
#pragma unroll
    for (int ks = 0; ks < 4; ++ks) {
      const float4* p = (const float4*)&hidn[m15][ks * 32 + quad * 8];
      float4 a = p[0], b = p[1];
      float f[8] = {a.x, a.y, a.z, a.w, b.x, b.y, b.z, b.w};
      split8(f, ga_hi[ks], ga_lo[ks]);
    }
    f32x4 acc = {0.f, 0.f, 0.f, 0.f};
#pragma unroll
    for (int ks = 0; ks < 4; ++ks) {
      float f[8];
#pragma unroll
      for (int j = 0; j < 8; ++j) {
        int k = ks * 32 + quad * 8 + j;
        f[j] = (m15 < OUTD) ? W_dec[(size_t)k * OUTD + m15] : 0.f;  // pad N 8->16
      }
      half8 bhi, blo;
      split8(f, bhi, blo);
      acc = MFMA(ga_hi[ks], bhi, acc);
      acc = MFMA(ga_lo[ks], bhi, acc);
      acc = MFMA(ga_hi[ks], blo, acc);
    }
    if (m15 < OUTD) {
      const float bd = b_dec[m15];
#pragma unroll
      for (int r = 0; r < 4; ++r) {
        const int m = quad * 4 + r;
        out[(size_t)(b0 + m) * OUTD + m15] = acc[r] + bd;
      }
    }
  }
}

extern "C" void kernel_launch(void* const* d_in, const int* in_sizes, int n_in,
                              void* d_out, int out_size, void* d_ws, size_t ws_size,
                              hipStream_t stream) {
  (void)in_sizes; (void)n_in; (void)d_ws; (void)ws_size; (void)out_size;
  const float* obs   = (const float*)d_in[0];
  const float* W_enc = (const float*)d_in[1];
  const float* b_enc = (const float*)d_in[2];
  const float* W_f   = (const float*)d_in[3];
  const float* b_f   = (const float*)d_in[4];
  const float* W_dec = (const float*)d_in[5];
  const float* b_dec = (const float*)d_in[6];
  float* out = (float*)d_out;

  dim3 grid(NB / BT);      // 2048 blocks
  dim3 block(THREADS);     // 256 threads = 4 waves
  gnn_fused<<<grid, block, 0, stream>>>(obs, W_enc, b_enc, W_f, b_f, W_dec, b_dec, out);
}